// Round 1
// baseline (2279.852 us; speedup 1.0000x reference)
//
#include <hip/hip_runtime.h>
#include <hip/hip_bf16.h>

typedef __hip_bfloat16 bf16;
typedef short v8s __attribute__((ext_vector_type(8)));
typedef float v4f __attribute__((ext_vector_type(4)));
typedef unsigned long long u64;

#define BATCH 256
#define SEQ 64
#define INPUT 512
#define HIDDEN 1024
#define CLASSES 1000

// ============================================================================
// Cross-block split-K LSTM.
//
// Fragment-linear layouts (bf16):
//   A-chunk (16 m x 32 k): chunk[lane*8+j] = A[m16*16+(lane&15)][k32*32+(lane>>4)*8+j]
//   B-chunk (16 n x 32 k): chunk[lane*8+j] = W[k32*32+(lane>>4)*8+j][ncol]
// Xfrag:  [t][m16(16)][k32(16)][512]
// h-frag: [t][m16(16)][k32(32)][512]   (deep-buffered, write-once per address)
// BfX:    [hb(128)][n16l(2)][k32(NT)][512]; hb covers h in [hb*8, hb*8+8):
//   n16l=0 cols = i-gate(8h), f-gate(8h); n16l=1 = g(8h), o(8h)
//
// Grid = 256 blocks x 512 thr. role = blockIdx>>6, cg = blockIdx&63 (64 cols
// = hb pair {2cg, 2cg+1}).
//   role 0 xW1: K=512,  A=Xf[t],        out: Z1 partial ring (+b1 folded)
//   role 1 U1 : K=1024, A=h1[t-1],      + Z1 partial -> epilogue -> h1[t]
//   role 2 U2 : K=1024, A=h2[t-1],      out: U2 partial ring
//   role 3 W2 : K=1024, A=h1[t],        + U2 partial + b2 -> epilogue -> h2[t]
// Wave tile: acc[2][4] = 2 m16 x 4 n16 (both hbs) -> A-bytes/MFMA halved vs
// acc[2][2]. Weights fully LDS-resident (<=128 KB). Partial rings depth 4,
// agent-scope atomic u64 both sides (immune to L2 staleness under reuse).
// h counters: target 64 publishers.
// ============================================================================

__global__ __launch_bounds__(256) void conv_x(const float* __restrict__ x,
                                              bf16* __restrict__ Xf) {
    int gid = blockIdx.x * 256 + threadIdx.x;
    int lane = gid & 63;
    int k32 = (gid >> 6) & 15;
    int m16 = (gid >> 10) & 15;
    int tt  = gid >> 14;
    int row = lane & 15, quad = lane >> 4;
    int b_ = m16 * 16 + row;
    int k  = k32 * 32 + quad * 8;
    const float* src = x + ((size_t)(b_ * SEQ + tt) * INPUT + k);
    float4 v0 = *(const float4*)src;
    float4 v1 = *(const float4*)(src + 4);
    bf16 o[8] = {__float2bfloat16(v0.x), __float2bfloat16(v0.y),
                 __float2bfloat16(v0.z), __float2bfloat16(v0.w),
                 __float2bfloat16(v1.x), __float2bfloat16(v1.y),
                 __float2bfloat16(v1.z), __float2bfloat16(v1.w)};
    bf16* dst = Xf + (size_t)(tt * 256 + m16 * 16 + k32) * 512 + lane * 8;
    *(v8s*)dst = *(v8s*)o;
}

// [W;U] fp32 -> Bf slices. grid (Ktot/64, 128, 2), block 256.
__global__ __launch_bounds__(256) void build_bf(const float* __restrict__ W,
                                                const float* __restrict__ U,
                                                int K0, int NT,
                                                bf16* __restrict__ dst) {
    __shared__ float tile[64][17];
    const int kt = blockIdx.x, hb = blockIdx.y, n16l = blockIdx.z;
    const int k0 = kt * 64;
    const int tid = threadIdx.x;
#pragma unroll
    for (int i = 0; i < 4; i++) {
        int idx = tid + i * 256;
        int c = idx & 15, kl = idx >> 4;
        int k = k0 + kl;
        int srccol = (n16l * 2 + (c >> 3)) * 1024 + hb * 8 + (c & 7);
        float v = (k < K0) ? W[(size_t)k * 4096 + srccol]
                           : U[(size_t)(k - K0) * 4096 + srccol];
        tile[kl][c] = v;
    }
    __syncthreads();
    if (tid < 128) {
        int k32l = tid >> 6, l = tid & 63;
        bf16 o[8];
#pragma unroll
        for (int j = 0; j < 8; j++)
            o[j] = __float2bfloat16(tile[k32l * 32 + (l >> 4) * 8 + j][l & 15]);
        *(v8s*)(dst + ((size_t)(hb * 2 + n16l) * NT + kt * 2 + k32l) * 512 + l * 8) = *(v8s*)o;
    }
}

__global__ __launch_bounds__(256) void build_wof(const float* __restrict__ Wo,
                                                 bf16* __restrict__ dst) {
    __shared__ float tile[64][17];
    const int h16 = blockIdx.y, kt = blockIdx.x;
    const int k0 = kt * 64, nb = h16 * 16;
    const int tid = threadIdx.x;
#pragma unroll
    for (int i = 0; i < 4; i++) {
        int idx = tid + i * 256;
        int kl = idx >> 4, c = idx & 15;
        int k = k0 + kl;
        float v = (nb + c < CLASSES) ? Wo[(size_t)k * CLASSES + nb + c] : 0.f;
        tile[kl][c] = v;
    }
    __syncthreads();
    if (tid < 128) {
        int k32l = tid >> 6, l = tid & 63;
        int col = l & 15, quad = l >> 4;
        bf16 o[8];
#pragma unroll
        for (int j = 0; j < 8; j++)
            o[j] = __float2bfloat16(tile[k32l * 32 + quad * 8 + j][col]);
        int k32 = kt * 2 + k32l;
        *(v8s*)(dst + (size_t)(h16 * 32 + k32) * 512 + l * 8) = *(v8s*)o;
    }
}

// ---------------------------------------------------------------------------
__device__ __forceinline__ void spinwait(const int* p, int target) {
    while (__hip_atomic_load(p, __ATOMIC_RELAXED, __HIP_MEMORY_SCOPE_AGENT) < target)
        __builtin_amdgcn_s_sleep(1);
}

// One K=NT*32 GEMM over the block's 256 rows x 64 cols. acc[mi][ni]:
// mi = m16 pair (wave*2+mi), ni = n16 (hb0-if, hb0-go, hb1-if, hb1-go).
template<int NT>
__device__ __forceinline__ void gemm_body(const bf16* __restrict__ A,
                                          const bf16* __restrict__ Bl,
                                          v4f acc[2][4], int tid) {
    const int lane = tid & 63, wave = tid >> 6;
    const bf16* a0 = A + (size_t)(wave * 2 + 0) * NT * 512 + lane * 8;
    const bf16* a1 = A + (size_t)(wave * 2 + 1) * NT * 512 + lane * 8;
    const bf16* bl = Bl + lane * 8;
    v8s ra[8][2];
    v8s rb[4][4];
#define IA(K, S) do {                                           \
    ra[S][0] = *(const v8s*)(a0 + (size_t)(K) * 512);           \
    ra[S][1] = *(const v8s*)(a1 + (size_t)(K) * 512);           \
} while (0)
#define IB(K, S) do {                                           \
    rb[S][0] = *(const v8s*)(bl + (size_t)(0 * NT + (K)) * 512);\
    rb[S][1] = *(const v8s*)(bl + (size_t)(1 * NT + (K)) * 512);\
    rb[S][2] = *(const v8s*)(bl + (size_t)(2 * NT + (K)) * 512);\
    rb[S][3] = *(const v8s*)(bl + (size_t)(3 * NT + (K)) * 512);\
} while (0)
#pragma unroll
    for (int k = 0; k < 8; k++) IA(k, k);
#pragma unroll
    for (int k = 0; k < 4; k++) IB(k, k);
#pragma unroll
    for (int k = 0; k < NT; k++) {
        const int sa = k & 7, sb = k & 3;
#pragma unroll
        for (int mi = 0; mi < 2; mi++)
#pragma unroll
            for (int ni = 0; ni < 4; ni++)
                acc[mi][ni] = __builtin_amdgcn_mfma_f32_16x16x32_bf16(
                    ra[sa][mi], rb[sb][ni], acc[mi][ni], 0, 0, 0);
        if (k + 8 < NT) IA(k + 8, sa);
        if (k + 4 < NT) IB(k + 4, sb);
    }
#undef IA
#undef IB
}

// Partial slot layout per (slot, cg): u64[(wave*16 + i)*64 + lane], 64 KB.
__device__ __forceinline__ void store_partial(u64* P, v4f acc[2][4], int tid) {
    const int lane = tid & 63, wave = tid >> 6;
    u64* p = P + (size_t)wave * 16 * 64 + lane;
#pragma unroll
    for (int mi = 0; mi < 2; mi++)
#pragma unroll
        for (int ni = 0; ni < 4; ni++) {
            u64 q[2];
            *(v4f*)q = acc[mi][ni];
            const int i0 = (ni * 2 + mi) * 2;
            __hip_atomic_store(p + (size_t)i0 * 64, q[0],
                               __ATOMIC_RELAXED, __HIP_MEMORY_SCOPE_AGENT);
            __hip_atomic_store(p + (size_t)(i0 + 1) * 64, q[1],
                               __ATOMIC_RELAXED, __HIP_MEMORY_SCOPE_AGENT);
        }
}

__device__ __forceinline__ void load_add_partial(const u64* P, v4f acc[2][4], int tid) {
    const int lane = tid & 63, wave = tid >> 6;
    const u64* p = P + (size_t)wave * 16 * 64 + lane;
#pragma unroll
    for (int mi = 0; mi < 2; mi++)
#pragma unroll
        for (int ni = 0; ni < 4; ni++) {
            const int i0 = (ni * 2 + mi) * 2;
            u64 q0 = __hip_atomic_load(p + (size_t)i0 * 64,
                                       __ATOMIC_RELAXED, __HIP_MEMORY_SCOPE_AGENT);
            u64 q1 = __hip_atomic_load(p + (size_t)(i0 + 1) * 64,
                                       __ATOMIC_RELAXED, __HIP_MEMORY_SCOPE_AGENT);
            acc[mi][ni][0] += __uint_as_float((unsigned)q0);
            acc[mi][ni][1] += __uint_as_float((unsigned)(q0 >> 32));
            acc[mi][ni][2] += __uint_as_float((unsigned)q1);
            acc[mi][ni][3] += __uint_as_float((unsigned)(q1 >> 32));
        }
}

// Gate exchange (lane^8), cell update in registers, h -> LDS transpose, then
// write-through flush of 16 h-cols into the h frag buffer for step t.
__device__ __forceinline__ void epi_flush(v4f acc[2][4], float cc[2][4],
                                          const float* bias, bf16* hstage,
                                          bf16* hout, int cg, int tid) {
    const int lane = tid & 63, wave = tid >> 6;
    const int col = lane & 15, quad = lane >> 4;
    const bool hicol = (col & 8) != 0;
#pragma unroll
    for (int hbs = 0; hbs < 2; hbs++) {
        float bI = 0.f, bF = 0.f, bG = 0.f, bO = 0.f;
        if (bias) {
            const int hc = (2 * cg + hbs) * 8 + (col & 7);
            bI = bias[hc];
            bF = bias[1024 + hc];
            bG = bias[2048 + hc];
            bO = bias[3072 + hc];
        }
        v4f A00 = acc[0][hbs * 2 + 0], A01 = acc[0][hbs * 2 + 1];
        v4f A10 = acc[1][hbs * 2 + 0], A11 = acc[1][hbs * 2 + 1];
#pragma unroll
        for (int r = 0; r < 4; r++) {
            float send0 = hicol ? A00[r] : A10[r];
            float send1 = hicol ? A01[r] : A11[r];
            float recv0 = __shfl_xor(send0, 8, 64);
            float recv1 = __shfl_xor(send1, 8, 64);
            float own0 = hicol ? A10[r] : A00[r];
            float own1 = hicol ? A11[r] : A01[r];
            float zi = (hicol ? recv0 : own0) + bI;
            float zf = (hicol ? own0 : recv0) + bF;
            float zg = (hicol ? recv1 : own1) + bG;
            float zo = (hicol ? own1 : recv1) + bO;
            float ig = 1.f / (1.f + __expf(-zi));
            float fg = 1.f / (1.f + __expf(-zf));
            float e2g = __expf(2.f * zg);
            float gg = (e2g - 1.f) / (e2g + 1.f);
            float og = 1.f / (1.f + __expf(-zo));
            float cn = fg * cc[hbs][r] + ig * gg;
            float e2c = __expf(2.f * cn);
            float th = (e2c - 1.f) / (e2c + 1.f);
            cc[hbs][r] = cn;
            int m_local = wave * 32 + (hicol ? 16 : 0) + quad * 4 + r;
            hstage[m_local * 16 + hbs * 8 + (col & 7)] = __float2bfloat16(og * th);
        }
    }
    // flush: lanes 0..31 emit one m-row (16 h = 32 B) write-through
    if (lane < 32) {
        int row = wave * 32 + lane;
        const int K32 = cg >> 1, Qb = (cg & 1) * 2;
        size_t base = ((size_t)(row >> 4) * 32 + K32) * 512;
        u64 q[2];
        v8s h0 = *(const v8s*)(hstage + row * 16);
        *(v8s*)q = h0;
        u64* dp = (u64*)(hout + base + (size_t)((row & 15) + 16 * Qb) * 8);
        __hip_atomic_store(dp, q[0], __ATOMIC_RELAXED, __HIP_MEMORY_SCOPE_AGENT);
        __hip_atomic_store(dp + 1, q[1], __ATOMIC_RELAXED, __HIP_MEMORY_SCOPE_AGENT);
        v8s h1 = *(const v8s*)(hstage + row * 16 + 8);
        *(v8s*)q = h1;
        dp = (u64*)(hout + base + (size_t)((row & 15) + 16 * (Qb + 1)) * 8);
        __hip_atomic_store(dp, q[0], __ATOMIC_RELAXED, __HIP_MEMORY_SCOPE_AGENT);
        __hip_atomic_store(dp + 1, q[1], __ATOMIC_RELAXED, __HIP_MEMORY_SCOPE_AGENT);
    }
}

__global__ __launch_bounds__(512, 2) void lstm_persist(
    const bf16* __restrict__ Xf,
    const bf16* __restrict__ BfW1, const bf16* __restrict__ BfU1,
    const bf16* __restrict__ BfW2, const bf16* __restrict__ BfU2,
    const float* __restrict__ b1, const float* __restrict__ b2,
    bf16* __restrict__ h1all, bf16* __restrict__ h2all,
    u64* __restrict__ Z1ring, u64* __restrict__ U2ring,
    int* __restrict__ flagsH1, int* __restrict__ flagsH2,
    int* __restrict__ flagsPZ, int* __restrict__ flagsPU)
{
    extern __shared__ char smem[];
    bf16* Bl = (bf16*)smem;
    bf16* hstage = (bf16*)(smem + 131072);

    const int b = blockIdx.x;
    const int role = b >> 6;
    const int cg = b & 63;
    const int tid = threadIdx.x;
    const size_t HB = (size_t)BATCH * HIDDEN;

    // one-time weight slice -> LDS (64 KB role 0, 128 KB others)
    {
        const bf16* src;
        int nbytes;
        if (role == 0)      { src = BfW1 + (size_t)cg * 4 * 16 * 512; nbytes = 4 * 16 * 1024; }
        else if (role == 1) { src = BfU1 + (size_t)cg * 4 * 32 * 512; nbytes = 4 * 32 * 1024; }
        else if (role == 2) { src = BfU2 + (size_t)cg * 4 * 32 * 512; nbytes = 4 * 32 * 1024; }
        else                { src = BfW2 + (size_t)cg * 4 * 32 * 512; nbytes = 4 * 32 * 1024; }
        for (int o = tid * 16; o < nbytes; o += 512 * 16)
            *(uint4*)(smem + o) = *(const uint4*)((const char*)src + o);
    }
    __syncthreads();

    if (role == 0) {
        // ---- xW1: Z = x_t @ W1 + b1 -> partial ring (sprints, ring depth 4) ----
        const int col = (tid & 63) & 15;
        float bni[4];
#pragma unroll
        for (int ni = 0; ni < 4; ni++)
            bni[ni] = b1[((ni & 1) * 2 + (col >> 3)) * 1024 + (2 * cg + (ni >> 1)) * 8 + (col & 7)];
        for (int t = 0; t < SEQ; t++) {
            if (tid == 0 && t >= 4) spinwait(flagsH1 + (t - 4) * 64, 64);  // slot free
            __syncthreads();
            v4f acc[2][4] = {};
            gemm_body<16>(Xf + (size_t)t * BATCH * INPUT, Bl, acc, tid);
#pragma unroll
            for (int mi = 0; mi < 2; mi++)
#pragma unroll
                for (int ni = 0; ni < 4; ni++)
#pragma unroll
                    for (int r = 0; r < 4; r++) acc[mi][ni][r] += bni[ni];
            store_partial(Z1ring + ((size_t)(t & 3) * 64 + cg) * 8192, acc, tid);
            __syncthreads();
            if (tid == 0)
                __hip_atomic_store(flagsPZ + (t & 3) * 64 + cg, t + 1,
                                   __ATOMIC_RELAXED, __HIP_MEMORY_SCOPE_AGENT);
        }
    } else if (role == 1) {
        // ---- U1: z1 = h1(t-1)@U1 + Z1 -> epilogue -> h1(t) ----
        float cc[2][4] = {};
        for (int t = 0; t < SEQ; t++) {
            if (tid == 0) {
                if (t) spinwait(flagsH1 + (t - 1) * 64, 64);
                spinwait(flagsPZ + (t & 3) * 64 + cg, t + 1);
            }
            __syncthreads();
            v4f acc[2][4] = {};
            if (t) gemm_body<32>(h1all + (size_t)(t - 1) * HB, Bl, acc, tid);
            load_add_partial(Z1ring + ((size_t)(t & 3) * 64 + cg) * 8192, acc, tid);
            epi_flush(acc, cc, nullptr, hstage, h1all + (size_t)t * HB, cg, tid);
            __syncthreads();   // drain write-through before publish
            if (tid == 0)
                __hip_atomic_fetch_add(flagsH1 + t * 64, 1,
                                       __ATOMIC_RELAXED, __HIP_MEMORY_SCOPE_AGENT);
        }
    } else if (role == 2) {
        // ---- U2: partial = h2(t-1)@U2 -> ring (slot reuse guarded by flagsH2 monotonicity) ----
        for (int t = 0; t < SEQ; t++) {
            if (tid == 0 && t) spinwait(flagsH2 + (t - 1) * 64, 64);
            __syncthreads();
            v4f acc[2][4] = {};
            if (t) gemm_body<32>(h2all + (size_t)(t - 1) * HB, Bl, acc, tid);
            store_partial(U2ring + ((size_t)(t & 3) * 64 + cg) * 8192, acc, tid);
            __syncthreads();
            if (tid == 0)
                __hip_atomic_store(flagsPU + (t & 3) * 64 + cg, t + 1,
                                   __ATOMIC_RELAXED, __HIP_MEMORY_SCOPE_AGENT);
        }
    } else {
        // ---- W2: z2 = h1(t)@W2 + U2partial + b2 -> epilogue -> h2(t) ----
        float cc[2][4] = {};
        for (int t = 0; t < SEQ; t++) {
            if (tid == 0) {
                spinwait(flagsH1 + t * 64, 64);
                spinwait(flagsPU + (t & 3) * 64 + cg, t + 1);
            }
            __syncthreads();
            v4f acc[2][4] = {};
            gemm_body<32>(h1all + (size_t)t * HB, Bl, acc, tid);
            load_add_partial(U2ring + ((size_t)(t & 3) * 64 + cg) * 8192, acc, tid);
            epi_flush(acc, cc, b2, hstage, h2all + (size_t)t * HB, cg, tid);
            __syncthreads();
            if (tid == 0)
                __hip_atomic_fetch_add(flagsH2 + t * 64, 1,
                                       __ATOMIC_RELAXED, __HIP_MEMORY_SCOPE_AGENT);
        }
    }
}

// ---------------- projection: out = h2(63) @ Wo + bo ----------------
__global__ __launch_bounds__(256, 2) void proj_kernel(
    const bf16* __restrict__ H,
    const bf16* __restrict__ Wof,
    const float* __restrict__ bo,
    float* __restrict__ Out)
{
    const int mblk = blockIdx.x, nblk = blockIdx.y;
    const int tid = threadIdx.x;
    const int lane = tid & 63;
    const int wave = tid >> 6;
    const int mw = wave >> 1, nw = wave & 1;
    const int col = lane & 15, quad = lane >> 4;

    const int m16 = mblk * 4 + mw * 2;
    const bf16* ah0 = H + (size_t)(m16 * 32) * 512 + lane * 8;
    const bf16* ah1 = H + (size_t)((m16 + 1) * 32) * 512 + lane * 8;
    const int n16a = nblk * 4 + nw * 2, n16b = n16a + 1;
    const bf16* bb0 = Wof + (size_t)(n16a * 32) * 512 + lane * 8;
    const bf16* bb1 = Wof + (size_t)(n16b * 32) * 512 + lane * 8;

    v4f acc00{}, acc01{}, acc10{}, acc11{};
    v8s ra0[8], ra1[8], rb0[8], rb1[8];

#define ISSUE(KK, SLOT) do {                          \
    const int kk_ = (KK);                             \
    ra0[SLOT] = *(const v8s*)(ah0 + kk_ * 512);       \
    ra1[SLOT] = *(const v8s*)(ah1 + kk_ * 512);       \
    rb0[SLOT] = *(const v8s*)(bb0 + kk_ * 512);       \
    rb1[SLOT] = *(const v8s*)(bb1 + kk_ * 512);       \
} while (0)

#pragma unroll
    for (int u = 0; u < 8; u++) ISSUE(u, u);

    for (int base = 0; base < 32; base += 8) {
#pragma unroll
        for (int u = 0; u < 8; u++) {
            acc00 = __builtin_amdgcn_mfma_f32_16x16x32_bf16(ra0[u], rb0[u], acc00, 0, 0, 0);
            acc01 = __builtin_amdgcn_mfma_f32_16x16x32_bf16(ra0[u], rb1[u], acc01, 0, 0, 0);
            acc10 = __builtin_amdgcn_mfma_f32_16x16x32_bf16(ra1[u], rb0[u], acc10, 0, 0, 0);
            acc11 = __builtin_amdgcn_mfma_f32_16x16x32_bf16(ra1[u], rb1[u], acc11, 0, 0, 0);
            const int k2 = base + u + 8;
            if (k2 < 32) ISSUE(k2, u);
        }
    }
#undef ISSUE

    const int n0 = n16a * 16 + col, n1 = n16b * 16 + col;
    const float bo0 = (n0 < CLASSES) ? bo[n0] : 0.f;
    const float bo1 = (n1 < CLASSES) ? bo[n1] : 0.f;
#pragma unroll
    for (int i = 0; i < 2; i++) {
        const int row = mblk * 64 + mw * 32 + i * 16 + quad * 4;
        v4f a0 = i ? acc10 : acc00;
        v4f a1 = i ? acc11 : acc01;
#pragma unroll
        for (int r = 0; r < 4; r++) {
            if (n0 < CLASSES) Out[(size_t)(row + r) * CLASSES + n0] = a0[r] + bo0;
            if (n1 < CLASSES) Out[(size_t)(row + r) * CLASSES + n1] = a1[r] + bo1;
        }
    }
}

// ---------------- launcher ----------------
extern "C" void kernel_launch(void* const* d_in, const int* in_sizes, int n_in,
                              void* d_out, int out_size, void* d_ws, size_t ws_size,
                              hipStream_t stream) {
    const float* x  = (const float*)d_in[0];
    const float* W1 = (const float*)d_in[1];
    const float* U1 = (const float*)d_in[2];
    const float* b1 = (const float*)d_in[3];
    const float* W2 = (const float*)d_in[4];
    const float* U2 = (const float*)d_in[5];
    const float* b2 = (const float*)d_in[6];
    const float* Wo = (const float*)d_in[7];
    const float* bo = (const float*)d_in[8];
    float* out = (float*)d_out;

    char* ws = (char*)d_ws;
    size_t off = 0;
    auto alloc = [&](size_t bytes) -> void* {
        void* p = ws + off;
        off += (bytes + 255) & ~(size_t)255;
        return p;
    };
    bf16* Xf    = (bf16*)alloc((size_t)SEQ * BATCH * INPUT * 2);     // 16.8 MB
    bf16* BfW1  = (bf16*)alloc((size_t)128 * 2 * 16 * 512 * 2);      // 4.2 MB
    bf16* BfU1  = (bf16*)alloc((size_t)128 * 2 * 32 * 512 * 2);      // 8.4 MB
    bf16* BfW2  = (bf16*)alloc((size_t)128 * 2 * 32 * 512 * 2);      // 8.4 MB
    bf16* BfU2  = (bf16*)alloc((size_t)128 * 2 * 32 * 512 * 2);      // 8.4 MB
    bf16* Wof   = (bf16*)alloc((size_t)64 * 32 * 512 * 2);           // 2 MB
    bf16* h1all = (bf16*)alloc((size_t)SEQ * BATCH * HIDDEN * 2);    // 33.6 MB
    bf16* h2all = (bf16*)alloc((size_t)SEQ * BATCH * HIDDEN * 2);    // 33.6 MB
    u64* Z1ring = (u64*)alloc((size_t)4 * 64 * 8192 * 8);            // 16.8 MB
    u64* U2ring = (u64*)alloc((size_t)4 * 64 * 8192 * 8);            // 16.8 MB
    int* flagsH1 = (int*)alloc(64 * 64 * 4);
    int* flagsH2 = (int*)alloc(64 * 64 * 4);
    int* flagsPZ = (int*)alloc(4 * 64 * 4);
    int* flagsPU = (int*)alloc(4 * 64 * 4);

    hipMemsetAsync(flagsH1, 0, 64 * 64 * 4, stream);
    hipMemsetAsync(flagsH2, 0, 64 * 64 * 4, stream);
    hipMemsetAsync(flagsPZ, 0, 4 * 64 * 4, stream);
    hipMemsetAsync(flagsPU, 0, 4 * 64 * 4, stream);

    conv_x<<<4096, 256, 0, stream>>>(x, Xf);
    build_bf<<<dim3(8, 128, 2), 256, 0, stream>>>(W1, W1, 512, 16, BfW1);
    build_bf<<<dim3(16, 128, 2), 256, 0, stream>>>(U1, U1, 0, 32, BfU1);
    build_bf<<<dim3(16, 128, 2), 256, 0, stream>>>(W2, W2, 1024, 32, BfW2);
    build_bf<<<dim3(16, 128, 2), 256, 0, stream>>>(U2, U2, 0, 32, BfU2);
    build_wof<<<dim3(16, 64), 256, 0, stream>>>(Wo, Wof);

    lstm_persist<<<256, 512, 139264, stream>>>(Xf, BfW1, BfU1, BfW2, BfU2,
                                               b1, b2, h1all, h2all,
                                               Z1ring, U2ring,
                                               flagsH1, flagsH2, flagsPZ, flagsPU);

    proj_kernel<<<dim3(4, 16), 256, 0, stream>>>(
        h2all + (size_t)(SEQ - 1) * BATCH * HIDDEN, Wof, bo, out);
}